// Round 4
// baseline (861.043 us; speedup 1.0000x reference)
//
#include <hip/hip_runtime.h>

#define L_SEQ 1024
#define DKV 64
#define NT 16

typedef float f32x4 __attribute__((ext_vector_type(4)));
typedef _Float16 f16x8 __attribute__((ext_vector_type(8)));
typedef _Float16 f16x4 __attribute__((ext_vector_type(4)));

#define QK_STRIDE 136   // f16 elems/row = 272 B (17*16 -> conflict-free b128 phases)
#define VT_STRIDE 72    // 144 B (9*16)
#define ATT_STRIDE 72   // 144 B

__device__ __forceinline__ f32x4 mfma16(f16x8 a, f16x8 b, f32x4 c) {
    return __builtin_amdgcn_mfma_f32_16x16x32_f16(a, b, c, 0, 0, 0);
}

__device__ __forceinline__ float fast_exp2(float x) {
#if __has_builtin(__builtin_amdgcn_exp2f)
    return __builtin_amdgcn_exp2f(x);
#else
    return exp2f(x);
#endif
}

__global__ __launch_bounds__(256, 2)
void fused_dual_attn(const float* __restrict__ Qg, const float* __restrict__ Kg,
                     const float* __restrict__ Vg, const float* __restrict__ Wg,
                     float* __restrict__ out_ctx, float* __restrict__ out_att)
{
    __shared__ _Float16 qk_lds[64 * QK_STRIDE];  // [kpos][0:64)=Q row, [64:128)=K row
    __shared__ _Float16 vt_lds[64 * VT_STRIDE];  // transposed V: [d][k]
    __shared__ _Float16 att_lds[64 * ATT_STRIDE];// attention tile f16: [q][k]

    const int tid  = (int)threadIdx.x;
    const int lane = tid & 63;
    const int w    = tid >> 6;      // wave 0..3
    const int wr   = w >> 1;        // row half (32 q rows)
    const int wc   = w & 1;         // col half (32 k cols)
    const int a    = lane & 15;
    const int g    = lane >> 4;

    // XCD-aware swizzle: 2048 wgs, 8 XCDs, 256 per chunk; bh contiguous per XCD
    const int bid = (int)blockIdx.x;
    const int sw  = (bid & 7) * 256 + (bid >> 3);
    const int bh  = sw >> 4;          // 0..127
    const int q0  = (sw & 15) * 64;   // q block base
    const int h   = bh & 7;

    const float SCALE_L2 = 0.125f * 1.44269504088896340736f; // scale * log2(e)

    const float* Qh = Qg + (size_t)bh * (L_SEQ * DKV);
    const float* Kh = Kg + (size_t)bh * (L_SEQ * DKV);
    const float* Vh = Vg + (size_t)bh * (L_SEQ * DKV);
    const float* Wh = Wg + (size_t)h * (L_SEQ * 2 * DKV);

    // ---- resident A fragments (this wave's 32 q rows), pre-scaled by scale*log2e ----
    f16x8 qa[2][2];   // Q rows, contraction d: [fr][kk]
    f16x8 wa[2][4];   // W rows, contraction c in 0..127: [fr][kk]
#pragma unroll
    for (int fr = 0; fr < 2; ++fr) {
        const int q = q0 + wr * 32 + fr * 16 + a;
        const float* qrow = Qh + q * DKV;
        const float* wrow = Wh + q * (2 * DKV);
#pragma unroll
        for (int kk = 0; kk < 2; ++kk) {
            const float* p = qrow + kk * 32 + g * 8;
            f32x4 lo = *(const f32x4*)p;
            f32x4 hi = *(const f32x4*)(p + 4);
            f16x8 v;
#pragma unroll
            for (int e = 0; e < 4; ++e) {
                v[e]     = (_Float16)(lo[e] * SCALE_L2);
                v[e + 4] = (_Float16)(hi[e] * SCALE_L2);
            }
            qa[fr][kk] = v;
        }
#pragma unroll
        for (int kk = 0; kk < 4; ++kk) {
            const float* p = wrow + kk * 32 + g * 8;
            f32x4 lo = *(const f32x4*)p;
            f32x4 hi = *(const f32x4*)(p + 4);
            f16x8 v;
#pragma unroll
            for (int e = 0; e < 4; ++e) {
                v[e]     = (_Float16)(lo[e] * SCALE_L2);
                v[e + 4] = (_Float16)(hi[e] * SCALE_L2);
            }
            wa[fr][kk] = v;
        }
    }

    auto stage_qk = [&](int t) {
#pragma unroll
        for (int i = 0; i < 8; ++i) {
            int u   = tid + i * 256;       // 0..2047
            int row = u >> 5;              // kpos within tile
            int c   = (u & 31) * 4;        // 0..124
            const float* src = (c < 64) ? (Qh + (t * 64 + row) * DKV + c)
                                        : (Kh + (t * 64 + row) * DKV + (c - 64));
            f32x4 x = *(const f32x4*)src;
            f16x4 y;
#pragma unroll
            for (int e = 0; e < 4; ++e) y[e] = (_Float16)x[e];
            *(f16x4*)&qk_lds[row * QK_STRIDE + c] = y;
        }
    };

    auto stage_vt = [&](int t) {
        const int kq = tid >> 4;  // 0..15 -> k = 4*kq
        const int dc = tid & 15;  // d chunk
        const float* base = Vh + (t * 64 + 4 * kq) * DKV + 4 * dc;
        f32x4 r0 = *(const f32x4*)(base);
        f32x4 r1 = *(const f32x4*)(base + DKV);
        f32x4 r2 = *(const f32x4*)(base + 2 * DKV);
        f32x4 r3 = *(const f32x4*)(base + 3 * DKV);
#pragma unroll
        for (int i = 0; i < 4; ++i) {
            f16x4 y = { (_Float16)r0[i], (_Float16)r1[i], (_Float16)r2[i], (_Float16)r3[i] };
            *(f16x4*)&vt_lds[(4 * dc + i) * VT_STRIDE + 4 * kq] = y;
        }
    };

    auto compute_scores = [&](f32x4 (&s1)[2][2], f32x4 (&s2)[2][2]) {
        f16x8 kb[2][2], qb[2][2];
#pragma unroll
        for (int fc = 0; fc < 2; ++fc) {
            const int kp = wc * 32 + fc * 16 + a;
            const _Float16* rowp = &qk_lds[kp * QK_STRIDE];
#pragma unroll
            for (int kk = 0; kk < 2; ++kk) {
                qb[fc][kk] = *(const f16x8*)(rowp + kk * 32 + g * 8);
                kb[fc][kk] = *(const f16x8*)(rowp + 64 + kk * 32 + g * 8);
            }
        }
        const f32x4 cinit = { -13.0f, -13.0f, -13.0f, -13.0f }; // static log2-domain offset
#pragma unroll
        for (int fr = 0; fr < 2; ++fr) {
#pragma unroll
            for (int fc = 0; fc < 2; ++fc) {
                f32x4 acc = cinit;
                acc = mfma16(qa[fr][0], kb[fc][0], acc);
                acc = mfma16(qa[fr][1], kb[fc][1], acc);
                s1[fr][fc] = acc;
                f32x4 acc2 = cinit;
                acc2 = mfma16(wa[fr][0], qb[fc][0], acc2); // W1 . Q[k]
                acc2 = mfma16(wa[fr][1], qb[fc][1], acc2);
                acc2 = mfma16(wa[fr][2], kb[fc][0], acc2); // W2 . K[k] (shared frags)
                acc2 = mfma16(wa[fr][3], kb[fc][1], acc2);
                s2[fr][fc] = acc2;
            }
        }
    };

    // ================= PASS 1: softmax denominators =================
    float lsum1[2][4] = {{0.f,0.f,0.f,0.f},{0.f,0.f,0.f,0.f}};
    float lsum2[2][4] = {{0.f,0.f,0.f,0.f},{0.f,0.f,0.f,0.f}};
    for (int t = 0; t < NT; ++t) {
        __syncthreads();
        stage_qk(t);
        __syncthreads();
        f32x4 s1[2][2], s2[2][2];
        compute_scores(s1, s2);
#pragma unroll
        for (int fr = 0; fr < 2; ++fr)
#pragma unroll
            for (int r = 0; r < 4; ++r) {
                lsum1[fr][r] += fast_exp2(s1[fr][0][r]) + fast_exp2(s1[fr][1][r]);
                lsum2[fr][r] += fast_exp2(s2[fr][0][r]) + fast_exp2(s2[fr][1][r]);
            }
    }

    // reduce over the 16 column-lanes
#pragma unroll
    for (int fr = 0; fr < 2; ++fr)
#pragma unroll
        for (int r = 0; r < 4; ++r) {
#pragma unroll
            for (int m = 1; m <= 8; m <<= 1) {
                lsum1[fr][r] += __shfl_xor(lsum1[fr][r], m, 64);
                lsum2[fr][r] += __shfl_xor(lsum2[fr][r], m, 64);
            }
        }

    // cross-wave merge (col halves) via LDS scratch (reuse qk_lds)
    float rinv1[2][4], rinv2[2][4];
    {
        float* sbuf = (float*)qk_lds;
        __syncthreads();
        if (a == 0) {
#pragma unroll
            for (int fr = 0; fr < 2; ++fr)
#pragma unroll
                for (int r = 0; r < 4; ++r) {
                    sbuf[w * 64 + fr * 16 + 4 * g + r]      = lsum1[fr][r];
                    sbuf[w * 64 + 32 + fr * 16 + 4 * g + r] = lsum2[fr][r];
                }
        }
        __syncthreads();
        const int pw = w ^ 1;
#pragma unroll
        for (int fr = 0; fr < 2; ++fr)
#pragma unroll
            for (int r = 0; r < 4; ++r) {
                float t1 = lsum1[fr][r] + sbuf[pw * 64 + fr * 16 + 4 * g + r];
                float t2 = lsum2[fr][r] + sbuf[pw * 64 + 32 + fr * 16 + 4 * g + r];
                rinv1[fr][r] = 1.0f / t1;
                rinv2[fr][r] = 1.0f / t2;
            }
    }

    // ================= PASS 2: attention out + fused PV =================
    f32x4 ctx[2][2] = {{{0.f,0.f,0.f,0.f},{0.f,0.f,0.f,0.f}},
                       {{0.f,0.f,0.f,0.f},{0.f,0.f,0.f,0.f}}};
    float* att_base = out_att + (size_t)bh * L_SEQ * L_SEQ;
    for (int t = 0; t < NT; ++t) {
        __syncthreads();   // prev PV done with vt/att; sbuf reads done (first iter)
        stage_qk(t);
        stage_vt(t);
        __syncthreads();
        f32x4 s1[2][2], s2[2][2];
        compute_scores(s1, s2);
#pragma unroll
        for (int fr = 0; fr < 2; ++fr)
#pragma unroll
            for (int fc = 0; fc < 2; ++fc) {
                const int kl = wc * 32 + fc * 16 + a;
                const int kp = t * 64 + kl;
#pragma unroll
                for (int r = 0; r < 4; ++r) {
                    const int ql = wr * 32 + fr * 16 + 4 * g + r;
                    float av = fast_exp2(s1[fr][fc][r]) * rinv1[fr][r]
                             + fast_exp2(s2[fr][fc][r]) * rinv2[fr][r];
                    att_base[(size_t)(q0 + ql) * L_SEQ + kp] = av;
                    att_lds[ql * ATT_STRIDE + kl] = (_Float16)av;
                }
            }
        __syncthreads();   // att tile complete for all 4 waves
#pragma unroll
        for (int kk = 0; kk < 2; ++kk) {
            f16x8 pa0 = *(const f16x8*)&att_lds[(wr * 32 + a) * ATT_STRIDE + kk * 32 + g * 8];
            f16x8 pa1 = *(const f16x8*)&att_lds[(wr * 32 + 16 + a) * ATT_STRIDE + kk * 32 + g * 8];
#pragma unroll
            for (int fc2 = 0; fc2 < 2; ++fc2) {
                f16x8 vb = *(const f16x8*)&vt_lds[(wc * 32 + fc2 * 16 + a) * VT_STRIDE + kk * 32 + g * 8];
                ctx[0][fc2] = mfma16(pa0, vb, ctx[0][fc2]);
                ctx[1][fc2] = mfma16(pa1, vb, ctx[1][fc2]);
            }
        }
    }

    // epilogue: context (d split across wc -> no cross-wave merge)
    float* ctx_base = out_ctx + (size_t)bh * L_SEQ * DKV;
#pragma unroll
    for (int fr = 0; fr < 2; ++fr)
#pragma unroll
        for (int fc2 = 0; fc2 < 2; ++fc2)
#pragma unroll
            for (int r = 0; r < 4; ++r) {
                const int q = q0 + wr * 32 + fr * 16 + 4 * g + r;
                const int d = wc * 32 + fc2 * 16 + a;
                ctx_base[(size_t)q * DKV + d] = ctx[fr][fc2][r];
            }
}

extern "C" void kernel_launch(void* const* d_in, const int* in_sizes, int n_in,
                              void* d_out, int out_size, void* d_ws, size_t ws_size,
                              hipStream_t stream) {
    const float* Q = (const float*)d_in[0];
    const float* K = (const float*)d_in[1];
    const float* V = (const float*)d_in[2];
    const float* W = (const float*)d_in[3];
    float* out_ctx = (float*)d_out;
    float* out_att = out_ctx + (size_t)16 * 8 * 1024 * 64; // 8,388,608
    fused_dual_attn<<<2048, 256, 0, stream>>>(Q, K, V, W, out_ctx, out_att);
}

// Round 5
// 802.765 us; speedup vs baseline: 1.0726x; 1.0726x over previous
//
#include <hip/hip_runtime.h>

#define L_SEQ 1024
#define DKV 64
#define NT 16

typedef float f32x4 __attribute__((ext_vector_type(4)));
typedef _Float16 f16x8 __attribute__((ext_vector_type(8)));
typedef _Float16 f16x4 __attribute__((ext_vector_type(4)));

#define QK_STRIDE 136   // f16 elems/row (272 B)
#define VT_STRIDE 76    // f16 elems/row (152 B) -> uniform bank spread for stage+read
#define ATT_STRIDE 80   // f16 elems/row (160 B) -> conflict-free P write/read

__device__ __forceinline__ f32x4 mfma16(f16x8 a, f16x8 b, f32x4 c) {
    return __builtin_amdgcn_mfma_f32_16x16x32_f16(a, b, c, 0, 0, 0);
}

__device__ __forceinline__ float fast_exp2(float x) {
#if __has_builtin(__builtin_amdgcn_exp2f)
    return __builtin_amdgcn_exp2f(x);
#else
    return exp2f(x);
#endif
}

__global__ __launch_bounds__(256, 2)
void fused_dual_attn(const float* __restrict__ Qg, const float* __restrict__ Kg,
                     const float* __restrict__ Vg, const float* __restrict__ Wg,
                     float* __restrict__ out_ctx, float* __restrict__ out_att)
{
    __shared__ _Float16 qk_lds[2][64 * QK_STRIDE];  // dbuf: [kpos][0:64)=Q, [64:128)=K
    __shared__ _Float16 vt_lds[2][64 * VT_STRIDE];  // dbuf: transposed V [d][k]
    __shared__ _Float16 att_lds[4][16 * ATT_STRIDE];// per-wave P tile [q16][k64]

    const int tid  = (int)threadIdx.x;
    const int lane = tid & 63;
    const int w    = tid >> 6;      // wave 0..3, owns 16 q rows
    const int a    = lane & 15;
    const int g    = lane >> 4;

    // XCD-aware swizzle: 2048 wgs, 8 XCDs, 256 per chunk; bh contiguous per XCD
    const int bid = (int)blockIdx.x;
    const int sw  = (bid & 7) * 256 + (bid >> 3);
    const int bh  = sw >> 4;          // 0..127
    const int q0  = (sw & 15) * 64;   // q block base
    const int h   = bh & 7;

    const float SCALE_L2 = 0.125f * 1.44269504088896340736f; // scale * log2(e)

    const float* Qh = Qg + (size_t)bh * (L_SEQ * DKV);
    const float* Kh = Kg + (size_t)bh * (L_SEQ * DKV);
    const float* Vh = Vg + (size_t)bh * (L_SEQ * DKV);
    const float* Wh = Wg + (size_t)h * (L_SEQ * 2 * DKV);

    // ---- resident A fragments: this wave's 16 q rows (row = q0 + w*16 + a) ----
    f16x8 qa[2];   // Q row, contraction d
    f16x8 wa[4];   // W row, contraction c in 0..127
    {
        const int q = q0 + w * 16 + a;
        const float* qrow = Qh + q * DKV;
        const float* wrow = Wh + q * (2 * DKV);
#pragma unroll
        for (int kk = 0; kk < 2; ++kk) {
            const float* p = qrow + kk * 32 + g * 8;
            f32x4 lo = *(const f32x4*)p;
            f32x4 hi = *(const f32x4*)(p + 4);
            f16x8 v;
#pragma unroll
            for (int e = 0; e < 4; ++e) {
                v[e]     = (_Float16)(lo[e] * SCALE_L2);
                v[e + 4] = (_Float16)(hi[e] * SCALE_L2);
            }
            qa[kk] = v;
        }
#pragma unroll
        for (int kk = 0; kk < 4; ++kk) {
            const float* p = wrow + kk * 32 + g * 8;
            f32x4 lo = *(const f32x4*)p;
            f32x4 hi = *(const f32x4*)(p + 4);
            f16x8 v;
#pragma unroll
            for (int e = 0; e < 4; ++e) {
                v[e]     = (_Float16)(lo[e] * SCALE_L2);
                v[e + 4] = (_Float16)(hi[e] * SCALE_L2);
            }
            wa[kk] = v;
        }
    }

    // ---- split staging: issue loads early, write LDS late (T14) ----
    f32x4 qkreg[8];
    auto qk_load = [&](int t) {
#pragma unroll
        for (int i = 0; i < 8; ++i) {
            int u   = tid + i * 256;       // 0..2047
            int row = u >> 5;
            int c   = (u & 31) * 4;
            const float* src = (c < 64) ? (Qh + (t * 64 + row) * DKV + c)
                                        : (Kh + (t * 64 + row) * DKV + (c - 64));
            qkreg[i] = *(const f32x4*)src;
        }
    };
    auto qk_store = [&](int b) {
#pragma unroll
        for (int i = 0; i < 8; ++i) {
            int u   = tid + i * 256;
            int row = u >> 5;
            int c   = (u & 31) * 4;
            f16x4 y;
#pragma unroll
            for (int e = 0; e < 4; ++e) y[e] = (_Float16)qkreg[i][e];
            *(f16x4*)&qk_lds[b][row * QK_STRIDE + c] = y;
        }
    };

    f32x4 vreg[4];
    auto vt_load = [&](int t) {
        const int kq = tid >> 4;
        const int dc = tid & 15;
        const float* base = Vh + (t * 64 + 4 * kq) * DKV + 4 * dc;
#pragma unroll
        for (int j = 0; j < 4; ++j) vreg[j] = *(const f32x4*)(base + j * DKV);
    };
    auto vt_store = [&](int b) {
        const int kq = tid >> 4;
        const int dc = tid & 15;
#pragma unroll
        for (int i = 0; i < 4; ++i) {
            f16x4 y = { (_Float16)vreg[0][i], (_Float16)vreg[1][i],
                        (_Float16)vreg[2][i], (_Float16)vreg[3][i] };
            *(f16x4*)&vt_lds[b][(4 * dc + i) * VT_STRIDE + 4 * kq] = y;
        }
    };

    // scores for this wave's 16 q rows x 64 k cols of tile in buffer b
    auto compute_scores = [&](int b, f32x4 (&s1)[4], f32x4 (&s2)[4]) {
        f16x8 kb[4][2], qb[4][2];
#pragma unroll
        for (int fc = 0; fc < 4; ++fc) {
            const _Float16* rowp = &qk_lds[b][(fc * 16 + a) * QK_STRIDE];
#pragma unroll
            for (int kk = 0; kk < 2; ++kk) {
                qb[fc][kk] = *(const f16x8*)(rowp + kk * 32 + g * 8);
                kb[fc][kk] = *(const f16x8*)(rowp + 64 + kk * 32 + g * 8);
            }
        }
        const f32x4 cinit = { -13.0f, -13.0f, -13.0f, -13.0f };
        __builtin_amdgcn_s_setprio(1);
#pragma unroll
        for (int fc = 0; fc < 4; ++fc) {
            f32x4 acc = cinit;
            acc = mfma16(qa[0], kb[fc][0], acc);
            acc = mfma16(qa[1], kb[fc][1], acc);
            s1[fc] = acc;
            f32x4 acc2 = cinit;
            acc2 = mfma16(wa[0], qb[fc][0], acc2); // W1 . Q[k]
            acc2 = mfma16(wa[1], qb[fc][1], acc2);
            acc2 = mfma16(wa[2], kb[fc][0], acc2); // W2 . K[k]
            acc2 = mfma16(wa[3], kb[fc][1], acc2);
            s2[fc] = acc2;
        }
        __builtin_amdgcn_s_setprio(0);
    };

    // ================= PASS 1: softmax denominators =================
    float lsum1[4] = {0.f, 0.f, 0.f, 0.f};
    float lsum2[4] = {0.f, 0.f, 0.f, 0.f};
    qk_load(0);
    qk_store(0);
    __syncthreads();
    for (int t = 0; t < NT; ++t) {
        if (t < NT - 1) qk_load(t + 1);
        f32x4 s1[4], s2[4];
        compute_scores(t & 1, s1, s2);
#pragma unroll
        for (int fc = 0; fc < 4; ++fc)
#pragma unroll
            for (int r = 0; r < 4; ++r) {
                lsum1[r] += fast_exp2(s1[fc][r]);
                lsum2[r] += fast_exp2(s2[fc][r]);
            }
        if (t < NT - 1) qk_store((t + 1) & 1);
        __syncthreads();
    }

    // wave-local reduce over 16 column-lanes (same g-group)
    float rinv1[4], rinv2[4];
#pragma unroll
    for (int r = 0; r < 4; ++r) {
#pragma unroll
        for (int m = 1; m <= 8; m <<= 1) {
            lsum1[r] += __shfl_xor(lsum1[r], m, 64);
            lsum2[r] += __shfl_xor(lsum2[r], m, 64);
        }
        rinv1[r] = 1.0f / lsum1[r];
        rinv2[r] = 1.0f / lsum2[r];
    }

    // ================= PASS 2: attention out + fused PV =================
    f32x4 ctx[4] = {{0.f,0.f,0.f,0.f},{0.f,0.f,0.f,0.f},
                    {0.f,0.f,0.f,0.f},{0.f,0.f,0.f,0.f}};
    float* att_base = out_att + (size_t)bh * L_SEQ * L_SEQ;
    _Float16* patt = &att_lds[w][0];

    qk_load(0);
    vt_load(0);
    qk_store(0);
    vt_store(0);
    __syncthreads();
    for (int t = 0; t < NT; ++t) {
        if (t < NT - 1) { qk_load(t + 1); vt_load(t + 1); }
        f32x4 s1[4], s2[4];
        compute_scores(t & 1, s1, s2);
        // normalized attention: write global (coalesced 64B runs) + wave-private LDS
#pragma unroll
        for (int fc = 0; fc < 4; ++fc)
#pragma unroll
            for (int r = 0; r < 4; ++r) {
                const int ql = 4 * g + r;   // local q row 0..15
                float av = fast_exp2(s1[fc][r]) * rinv1[r]
                         + fast_exp2(s2[fc][r]) * rinv2[r];
                att_base[(size_t)(q0 + w * 16 + ql) * L_SEQ + t * 64 + fc * 16 + a] = av;
                patt[ql * ATT_STRIDE + fc * 16 + a] = (_Float16)av;
            }
        // PV (wave-private P; compiler orders ds_write -> ds_read via lgkmcnt)
        __builtin_amdgcn_s_setprio(1);
#pragma unroll
        for (int kk = 0; kk < 2; ++kk) {
            f16x8 pa = *(const f16x8*)&patt[a * ATT_STRIDE + kk * 32 + g * 8];
#pragma unroll
            for (int fc2 = 0; fc2 < 4; ++fc2) {
                f16x8 vb = *(const f16x8*)&vt_lds[t & 1][(fc2 * 16 + a) * VT_STRIDE + kk * 32 + g * 8];
                ctx[fc2] = mfma16(pa, vb, ctx[fc2]);
            }
        }
        __builtin_amdgcn_s_setprio(0);
        if (t < NT - 1) { qk_store((t + 1) & 1); vt_store((t + 1) & 1); }
        __syncthreads();
    }

    // epilogue: context
    float* ctx_base = out_ctx + (size_t)bh * L_SEQ * DKV;
#pragma unroll
    for (int fc2 = 0; fc2 < 4; ++fc2)
#pragma unroll
        for (int r = 0; r < 4; ++r) {
            const int q = q0 + w * 16 + 4 * g + r;
            const int d = fc2 * 16 + a;
            ctx_base[(size_t)q * DKV + d] = ctx[fc2][r];
        }
}

extern "C" void kernel_launch(void* const* d_in, const int* in_sizes, int n_in,
                              void* d_out, int out_size, void* d_ws, size_t ws_size,
                              hipStream_t stream) {
    const float* Q = (const float*)d_in[0];
    const float* K = (const float*)d_in[1];
    const float* V = (const float*)d_in[2];
    const float* W = (const float*)d_in[3];
    float* out_ctx = (float*)d_out;
    float* out_att = out_ctx + (size_t)16 * 8 * 1024 * 64; // 8,388,608
    fused_dual_attn<<<2048, 256, 0, stream>>>(Q, K, V, W, out_ctx, out_att);
}

// Round 7
// 775.531 us; speedup vs baseline: 1.1103x; 1.0351x over previous
//
#include <hip/hip_runtime.h>

#define L_SEQ 1024
#define DKV 64
#define NT 16

typedef float f32x4 __attribute__((ext_vector_type(4)));
typedef _Float16 f16x8 __attribute__((ext_vector_type(8)));
typedef _Float16 f16x4 __attribute__((ext_vector_type(4)));

#define QK_STRIDE 136   // f16 elems/row (272 B)
#define VT_STRIDE 76    // f16 elems/row (152 B)
#define ATT_STRIDE 80   // f16 elems/row (160 B)

__device__ __forceinline__ f32x4 mfma16(f16x8 a, f16x8 b, f32x4 c) {
    return __builtin_amdgcn_mfma_f32_16x16x32_f16(a, b, c, 0, 0, 0);
}

__device__ __forceinline__ float fast_exp2(float x) {
#if __has_builtin(__builtin_amdgcn_exp2f)
    return __builtin_amdgcn_exp2f(x);
#else
    return exp2f(x);
#endif
}

__global__ __launch_bounds__(512, 2)
void fused_dual_attn(const float* __restrict__ Qg, const float* __restrict__ Kg,
                     const float* __restrict__ Vg, const float* __restrict__ Wg,
                     float* __restrict__ out_ctx, float* __restrict__ out_att)
{
    __shared__ _Float16 qk_lds[2][64 * QK_STRIDE];  // dbuf: [kpos][0:64)=Q, [64:128)=K
    __shared__ _Float16 vt_lds[2][64 * VT_STRIDE];  // dbuf: transposed V [d][k]
    __shared__ _Float16 att_lds[8][16 * ATT_STRIDE];// per-wave P tile [q16][k64]

    const int tid  = (int)threadIdx.x;
    const int lane = tid & 63;
    const int w    = tid >> 6;      // wave 0..7, owns 16 q rows
    const int a    = lane & 15;
    const int g    = lane >> 4;

    // XCD-aware swizzle: 1024 wgs, 8 XCDs, 128 per chunk; bh contiguous per XCD
    const int bid = (int)blockIdx.x;
    const int sw  = (bid & 7) * 128 + (bid >> 3);
    const int bh  = sw >> 3;          // 0..127
    const int q0  = (sw & 7) * 128;   // q block base (QBLK=128)
    const int h   = bh & 7;

    const float SCALE_L2 = 0.125f * 1.44269504088896340736f; // scale * log2(e)

    const float* Qh = Qg + (size_t)bh * (L_SEQ * DKV);
    const float* Kh = Kg + (size_t)bh * (L_SEQ * DKV);
    const float* Vh = Vg + (size_t)bh * (L_SEQ * DKV);
    const float* Wh = Wg + (size_t)h * (L_SEQ * 2 * DKV);

    // ---- resident A fragments: this wave's 16 q rows (row = q0 + w*16 + a) ----
    f16x8 qa[2];   // Q row, contraction d
    f16x8 wa[4];   // W row, contraction c in 0..127
    {
        const int q = q0 + w * 16 + a;
        const float* qrow = Qh + q * DKV;
        const float* wrow = Wh + q * (2 * DKV);
#pragma unroll
        for (int kk = 0; kk < 2; ++kk) {
            const float* p = qrow + kk * 32 + g * 8;
            f32x4 lo = *(const f32x4*)p;
            f32x4 hi = *(const f32x4*)(p + 4);
            f16x8 v;
#pragma unroll
            for (int e = 0; e < 4; ++e) {
                v[e]     = (_Float16)(lo[e] * SCALE_L2);
                v[e + 4] = (_Float16)(hi[e] * SCALE_L2);
            }
            qa[kk] = v;
        }
#pragma unroll
        for (int kk = 0; kk < 4; ++kk) {
            const float* p = wrow + kk * 32 + g * 8;
            f32x4 lo = *(const f32x4*)p;
            f32x4 hi = *(const f32x4*)(p + 4);
            f16x8 v;
#pragma unroll
            for (int e = 0; e < 4; ++e) {
                v[e]     = (_Float16)(lo[e] * SCALE_L2);
                v[e + 4] = (_Float16)(hi[e] * SCALE_L2);
            }
            wa[kk] = v;
        }
    }

    // ---- split staging: issue loads early, write LDS late (T14) ----
    f32x4 qkreg[4];
    auto qk_load = [&](int t) {
#pragma unroll
        for (int i = 0; i < 4; ++i) {
            int u   = tid + i * 512;       // 0..2047
            int row = u >> 5;
            int c   = (u & 31) * 4;
            const float* src = (c < 64) ? (Qh + (t * 64 + row) * DKV + c)
                                        : (Kh + (t * 64 + row) * DKV + (c - 64));
            qkreg[i] = *(const f32x4*)src;
        }
    };
    auto qk_store = [&](int b) {
#pragma unroll
        for (int i = 0; i < 4; ++i) {
            int u   = tid + i * 512;
            int row = u >> 5;
            int c   = (u & 31) * 4;
            f16x4 y;
#pragma unroll
            for (int e = 0; e < 4; ++e) y[e] = (_Float16)qkreg[i][e];
            *(f16x4*)&qk_lds[b][row * QK_STRIDE + c] = y;
        }
    };

    f32x4 vreg[4];   // only waves 0..3 use these
    auto vt_load = [&](int t) {
        const int kq = tid >> 4;   // 0..15 (tid < 256)
        const int dc = tid & 15;
        const float* base = Vh + (t * 64 + 4 * kq) * DKV + 4 * dc;
#pragma unroll
        for (int j = 0; j < 4; ++j) vreg[j] = *(const f32x4*)(base + j * DKV);
    };
    auto vt_store = [&](int b) {
        const int kq = tid >> 4;
        const int dc = tid & 15;
#pragma unroll
        for (int i = 0; i < 4; ++i) {
            f16x4 y = { (_Float16)vreg[0][i], (_Float16)vreg[1][i],
                        (_Float16)vreg[2][i], (_Float16)vreg[3][i] };
            *(f16x4*)&vt_lds[b][(4 * dc + i) * VT_STRIDE + 4 * kq] = y;
        }
    };

    // scores for this wave's 16 q rows x 64 k cols of tile in buffer b
    auto compute_scores = [&](int b, f32x4 (&s1)[4], f32x4 (&s2)[4]) {
        f16x8 kb[4][2], qb[4][2];
#pragma unroll
        for (int fc = 0; fc < 4; ++fc) {
            const _Float16* rowp = &qk_lds[b][(fc * 16 + a) * QK_STRIDE];
#pragma unroll
            for (int kk = 0; kk < 2; ++kk) {
                qb[fc][kk] = *(const f16x8*)(rowp + kk * 32 + g * 8);
                kb[fc][kk] = *(const f16x8*)(rowp + 64 + kk * 32 + g * 8);
            }
        }
        const f32x4 cinit = { -13.0f, -13.0f, -13.0f, -13.0f };
        __builtin_amdgcn_s_setprio(1);
#pragma unroll
        for (int fc = 0; fc < 4; ++fc) {
            f32x4 acc = cinit;
            acc = mfma16(qa[0], kb[fc][0], acc);
            acc = mfma16(qa[1], kb[fc][1], acc);
            s1[fc] = acc;
            f32x4 acc2 = cinit;
            acc2 = mfma16(wa[0], qb[fc][0], acc2); // W1 . Q[k]
            acc2 = mfma16(wa[1], qb[fc][1], acc2);
            acc2 = mfma16(wa[2], kb[fc][0], acc2); // W2 . K[k]
            acc2 = mfma16(wa[3], kb[fc][1], acc2);
            s2[fc] = acc2;
        }
        __builtin_amdgcn_s_setprio(0);
    };

    // ================= PASS 1: softmax denominators =================
    float lsum1[4] = {0.f, 0.f, 0.f, 0.f};
    float lsum2[4] = {0.f, 0.f, 0.f, 0.f};
    qk_load(0);
    qk_store(0);
    __syncthreads();
    for (int t = 0; t < NT; ++t) {
        if (t < NT - 1) qk_load(t + 1);
        f32x4 s1[4], s2[4];
        compute_scores(t & 1, s1, s2);
#pragma unroll
        for (int fc = 0; fc < 4; ++fc)
#pragma unroll
            for (int r = 0; r < 4; ++r) {
                lsum1[r] += fast_exp2(s1[fc][r]);
                lsum2[r] += fast_exp2(s2[fc][r]);
            }
        if (t < NT - 1) qk_store((t + 1) & 1);
        __syncthreads();
    }

    // wave-local reduce over 16 column-lanes (same g-group)
    float rinv1[4], rinv2[4];
#pragma unroll
    for (int r = 0; r < 4; ++r) {
#pragma unroll
        for (int m = 1; m <= 8; m <<= 1) {
            lsum1[r] += __shfl_xor(lsum1[r], m, 64);
            lsum2[r] += __shfl_xor(lsum2[r], m, 64);
        }
        rinv1[r] = 1.0f / lsum1[r];
        rinv2[r] = 1.0f / lsum2[r];
    }

    // ================= PASS 2: attention out + fused PV =================
    f32x4 ctx[4] = {{0.f,0.f,0.f,0.f},{0.f,0.f,0.f,0.f},
                    {0.f,0.f,0.f,0.f},{0.f,0.f,0.f,0.f}};
    float* att_base = out_att + (size_t)bh * L_SEQ * L_SEQ;
    _Float16* patt = &att_lds[w][0];

    qk_load(0);
    if (tid < 256) vt_load(0);
    qk_store(0);
    if (tid < 256) vt_store(0);
    __syncthreads();
    for (int t = 0; t < NT; ++t) {
        if (t < NT - 1) { qk_load(t + 1); if (tid < 256) vt_load(t + 1); }
        f32x4 s1[4], s2[4];
        compute_scores(t & 1, s1, s2);
        // normalized attention: write global + wave-private LDS
#pragma unroll
        for (int fc = 0; fc < 4; ++fc)
#pragma unroll
            for (int r = 0; r < 4; ++r) {
                const int ql = 4 * g + r;   // local q row 0..15
                float av = fast_exp2(s1[fc][r]) * rinv1[r]
                         + fast_exp2(s2[fc][r]) * rinv2[r];
                att_base[(size_t)(q0 + w * 16 + ql) * L_SEQ + t * 64 + fc * 16 + a] = av;
                patt[ql * ATT_STRIDE + fc * 16 + a] = (_Float16)av;
            }
        // PV (wave-private P; compiler orders ds_write -> ds_read via lgkmcnt)
        __builtin_amdgcn_s_setprio(1);
#pragma unroll
        for (int kk = 0; kk < 2; ++kk) {
            f16x8 pa = *(const f16x8*)&patt[a * ATT_STRIDE + kk * 32 + g * 8];
#pragma unroll
            for (int fc2 = 0; fc2 < 4; ++fc2) {
                f16x8 vb = *(const f16x8*)&vt_lds[t & 1][(fc2 * 16 + a) * VT_STRIDE + kk * 32 + g * 8];
                ctx[fc2] = mfma16(pa, vb, ctx[fc2]);
            }
        }
        __builtin_amdgcn_s_setprio(0);
        if (t < NT - 1) { qk_store((t + 1) & 1); if (tid < 256) vt_store((t + 1) & 1); }
        __syncthreads();
    }

    // epilogue: context
    float* ctx_base = out_ctx + (size_t)bh * L_SEQ * DKV;
#pragma unroll
    for (int fc2 = 0; fc2 < 4; ++fc2)
#pragma unroll
        for (int r = 0; r < 4; ++r) {
            const int q = q0 + w * 16 + 4 * g + r;
            const int d = fc2 * 16 + a;
            ctx_base[(size_t)q * DKV + d] = ctx[fc2][r];
        }
}

extern "C" void kernel_launch(void* const* d_in, const int* in_sizes, int n_in,
                              void* d_out, int out_size, void* d_ws, size_t ws_size,
                              hipStream_t stream) {
    const float* Q = (const float*)d_in[0];
    const float* K = (const float*)d_in[1];
    const float* V = (const float*)d_in[2];
    const float* W = (const float*)d_in[3];
    float* out_ctx = (float*)d_out;
    float* out_att = out_ctx + (size_t)16 * 8 * 1024 * 64; // 8,388,608
    fused_dual_attn<<<1024, 512, 0, stream>>>(Q, K, V, W, out_ctx, out_att);
}

// Round 8
// 759.709 us; speedup vs baseline: 1.1334x; 1.0208x over previous
//
#include <hip/hip_runtime.h>

#define L_SEQ 1024
#define DKV 64
#define NT 16

typedef float f32x4 __attribute__((ext_vector_type(4)));
typedef _Float16 f16x8 __attribute__((ext_vector_type(8)));
typedef _Float16 f16x4 __attribute__((ext_vector_type(4)));

#define QK_STRIDE 136   // f16 elems/row (272 B)
#define VT_STRIDE 76    // f16 elems/row (152 B)
#define ATT_STRIDE 72   // f16 elems/row (144 B, 16B-aligned rows)

__device__ __forceinline__ f32x4 mfma16(f16x8 a, f16x8 b, f32x4 c) {
    return __builtin_amdgcn_mfma_f32_16x16x32_f16(a, b, c, 0, 0, 0);
}

__device__ __forceinline__ float fast_exp2(float x) {
#if __has_builtin(__builtin_amdgcn_exp2f)
    return __builtin_amdgcn_exp2f(x);
#else
    return exp2f(x);
#endif
}

// barrier that drains LDS ops only — lets global (att) stores float across (T4)
__device__ __forceinline__ void barrier_lgkm() {
    __builtin_amdgcn_sched_barrier(0);
    asm volatile("s_waitcnt lgkmcnt(0)" ::: "memory");
    __builtin_amdgcn_s_barrier();
    __builtin_amdgcn_sched_barrier(0);
}

__global__ __launch_bounds__(512, 2)
void fused_dual_attn(const float* __restrict__ Qg, const float* __restrict__ Kg,
                     const float* __restrict__ Vg, const float* __restrict__ Wg,
                     float* __restrict__ out_ctx, float* __restrict__ out_att)
{
    __shared__ _Float16 qk_lds[2][64 * QK_STRIDE];  // dbuf: [kpos][0:64)=Q, [64:128)=K
    __shared__ _Float16 vt_lds[2][64 * VT_STRIDE];  // dbuf: transposed V [d][k]
    __shared__ _Float16 att_lds[8][16 * ATT_STRIDE];// per-wave P tile [q16][k64]

    const int tid  = (int)threadIdx.x;
    const int lane = tid & 63;
    const int w    = tid >> 6;      // wave 0..7, owns 16 q rows
    const int a    = lane & 15;
    const int g    = lane >> 4;

    // XCD-aware swizzle: 1024 wgs, 8 XCDs, 128 per chunk; bh contiguous per XCD
    const int bid = (int)blockIdx.x;
    const int sw  = (bid & 7) * 128 + (bid >> 3);
    const int bh  = sw >> 3;          // 0..127
    const int q0  = (sw & 7) * 128;   // q block base (QBLK=128)
    const int h   = bh & 7;

    const float SCALE_L2 = 0.125f * 1.44269504088896340736f; // scale * log2(e)

    const float* Qh = Qg + (size_t)bh * (L_SEQ * DKV);
    const float* Kh = Kg + (size_t)bh * (L_SEQ * DKV);
    const float* Vh = Vg + (size_t)bh * (L_SEQ * DKV);
    const float* Wh = Wg + (size_t)h * (L_SEQ * 2 * DKV);

    // ---- resident fragments: this wave's 16 q rows (row = q0 + w*16 + a) ----
    f16x8 qa[2];   // Q row (used as B-operand: own idx = a = q)
    f16x8 wa[4];   // W row (used as B-operand), contraction c in 0..127
    {
        const int q = q0 + w * 16 + a;
        const float* qrow = Qh + q * DKV;
        const float* wrow = Wh + q * (2 * DKV);
#pragma unroll
        for (int kk = 0; kk < 2; ++kk) {
            const float* p = qrow + kk * 32 + g * 8;
            f32x4 lo = *(const f32x4*)p;
            f32x4 hi = *(const f32x4*)(p + 4);
            f16x8 v;
#pragma unroll
            for (int e = 0; e < 4; ++e) {
                v[e]     = (_Float16)(lo[e] * SCALE_L2);
                v[e + 4] = (_Float16)(hi[e] * SCALE_L2);
            }
            qa[kk] = v;
        }
#pragma unroll
        for (int kk = 0; kk < 4; ++kk) {
            const float* p = wrow + kk * 32 + g * 8;
            f32x4 lo = *(const f32x4*)p;
            f32x4 hi = *(const f32x4*)(p + 4);
            f16x8 v;
#pragma unroll
            for (int e = 0; e < 4; ++e) {
                v[e]     = (_Float16)(lo[e] * SCALE_L2);
                v[e + 4] = (_Float16)(hi[e] * SCALE_L2);
            }
            wa[kk] = v;
        }
    }

    // ---- split staging: issue loads early, write LDS late (T14) ----
    f32x4 qkreg[4];
    auto qk_load = [&](int t) {
#pragma unroll
        for (int i = 0; i < 4; ++i) {
            int u   = tid + i * 512;       // 0..2047
            int row = u >> 5;
            int c   = (u & 31) * 4;
            const float* src = (c < 64) ? (Qh + (t * 64 + row) * DKV + c)
                                        : (Kh + (t * 64 + row) * DKV + (c - 64));
            qkreg[i] = *(const f32x4*)src;
        }
    };
    auto qk_store = [&](int b) {
#pragma unroll
        for (int i = 0; i < 4; ++i) {
            int u   = tid + i * 512;
            int row = u >> 5;
            int c   = (u & 31) * 4;
            f16x4 y;
#pragma unroll
            for (int e = 0; e < 4; ++e) y[e] = (_Float16)qkreg[i][e];
            *(f16x4*)&qk_lds[b][row * QK_STRIDE + c] = y;
        }
    };

    f32x4 vreg[4];   // only waves 0..3 use these
    auto vt_load = [&](int t) {
        const int kq = tid >> 4;   // 0..15 (tid < 256)
        const int dc = tid & 15;
        const float* base = Vh + (t * 64 + 4 * kq) * DKV + 4 * dc;
#pragma unroll
        for (int j = 0; j < 4; ++j) vreg[j] = *(const f32x4*)(base + j * DKV);
    };
    auto vt_store = [&](int b) {
        const int kq = tid >> 4;
        const int dc = tid & 15;
#pragma unroll
        for (int i = 0; i < 4; ++i) {
            f16x4 y = { (_Float16)vreg[0][i], (_Float16)vreg[1][i],
                        (_Float16)vreg[2][i], (_Float16)vreg[3][i] };
            *(f16x4*)&vt_lds[b][(4 * dc + i) * VT_STRIDE + 4 * kq] = y;
        }
    };

    // SWAPPED scores: C[col = q = a][row = k = fc*16 + 4g + r]
    auto compute_scores = [&](int b, f32x4 (&s1)[4], f32x4 (&s2)[4]) {
        f16x8 kb[4][2], qb[4][2];
#pragma unroll
        for (int fc = 0; fc < 4; ++fc) {
            const _Float16* rowp = &qk_lds[b][(fc * 16 + a) * QK_STRIDE];
#pragma unroll
            for (int kk = 0; kk < 2; ++kk) {
                qb[fc][kk] = *(const f16x8*)(rowp + kk * 32 + g * 8);
                kb[fc][kk] = *(const f16x8*)(rowp + 64 + kk * 32 + g * 8);
            }
        }
        const f32x4 cinit = { -13.0f, -13.0f, -13.0f, -13.0f };
        __builtin_amdgcn_s_setprio(1);
#pragma unroll
        for (int fc = 0; fc < 4; ++fc) {
            f32x4 acc = cinit;
            acc = mfma16(kb[fc][0], qa[0], acc);   // K-rows x Q-cols
            acc = mfma16(kb[fc][1], qa[1], acc);
            s1[fc] = acc;
            f32x4 acc2 = cinit;
            acc2 = mfma16(qb[fc][0], wa[0], acc2); // Q[k]-rows x W1-cols
            acc2 = mfma16(qb[fc][1], wa[1], acc2);
            acc2 = mfma16(kb[fc][0], wa[2], acc2); // K[k]-rows x W2-cols
            acc2 = mfma16(kb[fc][1], wa[3], acc2);
            s2[fc] = acc2;
        }
        __builtin_amdgcn_s_setprio(0);
    };

    // ================= PASS 1: softmax denominators =================
    float lsum1 = 0.f, lsum2 = 0.f;   // partial row-sum for q = q0+w*16+a
    qk_load(0);
    qk_store(0);
    __syncthreads();
    for (int t = 0; t < NT; ++t) {
        if (t < NT - 1) qk_load(t + 1);
        f32x4 s1[4], s2[4];
        compute_scores(t & 1, s1, s2);
#pragma unroll
        for (int fc = 0; fc < 4; ++fc)
#pragma unroll
            for (int r = 0; r < 4; ++r) {
                lsum1 += fast_exp2(s1[fc][r]);
                lsum2 += fast_exp2(s2[fc][r]);
            }
        if (t < NT - 1) qk_store((t + 1) & 1);
        barrier_lgkm();
    }

    // reduce across the 4 g-groups (lanes a, a+16, a+32, a+48)
    lsum1 += __shfl_xor(lsum1, 16, 64);
    lsum1 += __shfl_xor(lsum1, 32, 64);
    lsum2 += __shfl_xor(lsum2, 16, 64);
    lsum2 += __shfl_xor(lsum2, 32, 64);
    const float rinv1 = 1.0f / lsum1;
    const float rinv2 = 1.0f / lsum2;

    // ================= PASS 2: attention out + fused PV =================
    f32x4 ctx[4] = {{0.f,0.f,0.f,0.f},{0.f,0.f,0.f,0.f},
                    {0.f,0.f,0.f,0.f},{0.f,0.f,0.f,0.f}};
    float* att_row = out_att + (size_t)bh * L_SEQ * L_SEQ
                             + (size_t)(q0 + w * 16 + a) * L_SEQ;
    _Float16* patt = &att_lds[w][0];

    qk_load(0);
    if (tid < 256) vt_load(0);
    qk_store(0);
    if (tid < 256) vt_store(0);
    __syncthreads();
    for (int t = 0; t < NT; ++t) {
        if (t < NT - 1) { qk_load(t + 1); if (tid < 256) vt_load(t + 1); }
        f32x4 s1[4], s2[4];
        compute_scores(t & 1, s1, s2);
        // normalized attention: thread holds 4 contiguous k for its q row
#pragma unroll
        for (int fc = 0; fc < 4; ++fc) {
            f32x4 avv;
#pragma unroll
            for (int r = 0; r < 4; ++r)
                avv[r] = fast_exp2(s1[fc][r]) * rinv1 + fast_exp2(s2[fc][r]) * rinv2;
            *(f32x4*)&att_row[t * 64 + fc * 16 + g * 4] = avv;   // 16B vector store
            f16x4 ph = { (_Float16)avv[0], (_Float16)avv[1],
                         (_Float16)avv[2], (_Float16)avv[3] };
            *(f16x4*)&patt[a * ATT_STRIDE + fc * 16 + g * 4] = ph;
        }
        // PV (wave-private P; same-wave lgkm deps ordered by compiler)
        __builtin_amdgcn_s_setprio(1);
#pragma unroll
        for (int kk = 0; kk < 2; ++kk) {
            f16x8 pa = *(const f16x8*)&patt[a * ATT_STRIDE + kk * 32 + g * 8];
#pragma unroll
            for (int fc2 = 0; fc2 < 4; ++fc2) {
                f16x8 vb = *(const f16x8*)&vt_lds[t & 1][(fc2 * 16 + a) * VT_STRIDE + kk * 32 + g * 8];
                ctx[fc2] = mfma16(pa, vb, ctx[fc2]);
            }
        }
        __builtin_amdgcn_s_setprio(0);
        if (t < NT - 1) { qk_store((t + 1) & 1); if (tid < 256) vt_store((t + 1) & 1); }
        barrier_lgkm();
    }

    // epilogue: context (ctx C-layout: col=d=a from vb, row=q=4g+r from pa)
    float* ctx_base = out_ctx + (size_t)bh * L_SEQ * DKV;
#pragma unroll
    for (int fc2 = 0; fc2 < 4; ++fc2)
#pragma unroll
        for (int r = 0; r < 4; ++r) {
            const int q = q0 + w * 16 + 4 * g + r;
            const int d = fc2 * 16 + a;
            ctx_base[(size_t)q * DKV + d] = ctx[fc2][r];
        }
}

extern "C" void kernel_launch(void* const* d_in, const int* in_sizes, int n_in,
                              void* d_out, int out_size, void* d_ws, size_t ws_size,
                              hipStream_t stream) {
    const float* Q = (const float*)d_in[0];
    const float* K = (const float*)d_in[1];
    const float* V = (const float*)d_in[2];
    const float* W = (const float*)d_in[3];
    float* out_ctx = (float*)d_out;
    float* out_att = out_ctx + (size_t)16 * 8 * 1024 * 64; // 8,388,608
    fused_dual_attn<<<1024, 512, 0, stream>>>(Q, K, V, W, out_ctx, out_att);
}